// Round 1
// baseline (287.693 us; speedup 1.0000x reference)
//
#include <hip/hip_runtime.h>

typedef float f32x4 __attribute__((ext_vector_type(4)));
typedef short s16x8 __attribute__((ext_vector_type(8)));
typedef short s16x4 __attribute__((ext_vector_type(4)));
typedef unsigned short ushort_t;

#define L_TOT 1360
#define BROWS 5440   // 4 * 1360
#define DM    1024

__device__ __forceinline__ float b2f(ushort_t u){
  union { unsigned int u; float f; } v; v.u = ((unsigned int)u) << 16; return v.f;
}
__device__ __forceinline__ ushort_t f2bf(float f){
  union { float f; unsigned int u; } v; v.f = f;
  unsigned int u = v.u;
  unsigned int r = u + 0x7fffu + ((u >> 16) & 1u);   // round-to-nearest-even
  return (ushort_t)(r >> 16);
}

// ---------------------------------------------------------------- LayerNorm
// One block per row. Writes LN(x) as bf16 (A-operand of the Q GEMM).
__global__ __launch_bounds__(256) void ln_kernel(const float* __restrict__ x,
    const float* __restrict__ gamma, const float* __restrict__ beta,
    ushort_t* __restrict__ xln){
  const int row = blockIdx.x;
  const int t = threadIdx.x;
  const float* xr = x + (size_t)row * DM;
  f32x4 v = *reinterpret_cast<const f32x4*>(xr + t * 4);
  float s  = v.x + v.y + v.z + v.w;
  float s2 = v.x*v.x + v.y*v.y + v.z*v.z + v.w*v.w;
  #pragma unroll
  for (int off = 32; off; off >>= 1){ s += __shfl_xor(s, off); s2 += __shfl_xor(s2, off); }
  __shared__ float red[8];
  const int wid = t >> 6, lane = t & 63;
  if (lane == 0){ red[wid] = s; red[4 + wid] = s2; }
  __syncthreads();
  s  = red[0] + red[1] + red[2] + red[3];
  s2 = red[4] + red[5] + red[6] + red[7];
  const float mu  = s * (1.0f / DM);
  const float var = s2 * (1.0f / DM) - mu * mu;
  const float rs  = rsqrtf(var + 1e-6f);
  ushort_t o[4];
  #pragma unroll
  for (int j = 0; j < 4; j++){
    const int c = t * 4 + j;
    const float y = (v[j] - mu) * rs * gamma[c] + beta[c];
    o[j] = f2bf(y);
  }
  *reinterpret_cast<uint2*>(xln + (size_t)row * DM + t * 4) = *reinterpret_cast<const uint2*>(o);
}

// ---------------------------------------------------------------- GEMM
// C[5440 x 1024] = A[5440 x 1024] * B[1024 x 1024]
// BM=128, BN=64, BK=32; 4 waves (2x2), each wave 64x32 via 4x2 16x16 frags.
// A staged in LDS (bf16, stride 40 to dodge bank conflicts); B fragments read
// straight from global f32 (weight k-slab is L1/L2 resident) and cvt to bf16.
// MODE 0: store bf16 C * scale.  MODE 1: store f32 C + bias + residual.
#define BM 128
#define BN 64
#define BK 32
#define LDAS 40

template<bool ABF16, int MODE>
__global__ __launch_bounds__(256) void gemm_kernel(const void* __restrict__ Ap,
    const float* __restrict__ B, ushort_t* __restrict__ Cb, float* __restrict__ Cf,
    const float* __restrict__ bias, const float* __restrict__ resid, float scale){
  __shared__ __align__(16) ushort_t As[BM * LDAS];
  const int tid = threadIdx.x;
  const int wid = tid >> 6, lane = tid & 63;
  const int l15 = lane & 15, lg = lane >> 4;
  const int wr = wid >> 1, wc = wid & 1;
  const int m0 = blockIdx.y * BM, n0 = blockIdx.x * BN;
  const ushort_t* Ab = (const ushort_t*)Ap;
  const float*    Af = (const float*)Ap;

  f32x4 acc[4][2];
  #pragma unroll
  for (int a = 0; a < 4; a++)
    #pragma unroll
    for (int b = 0; b < 2; b++) acc[a][b] = (f32x4){0.f, 0.f, 0.f, 0.f};

  for (int kt = 0; kt < DM / BK; ++kt){
    const int k0 = kt * BK;
    __syncthreads();           // protect As reads of previous iter
    { // stage A tile: 128x32 bf16, 256 threads x 2 passes x 8 elems
      const int r = tid >> 2, c8 = (tid & 3) * 8;
      #pragma unroll
      for (int p = 0; p < 2; p++){
        const int rr = r + 64 * p;
        int grow = m0 + rr; if (grow > BROWS - 1) grow = BROWS - 1;  // clamp ragged tile
        s16x8 val;
        if (ABF16){
          val = *reinterpret_cast<const s16x8*>(Ab + (size_t)grow * DM + k0 + c8);
        } else {
          f32x4 f0 = *reinterpret_cast<const f32x4*>(Af + (size_t)grow * DM + k0 + c8);
          f32x4 f1 = *reinterpret_cast<const f32x4*>(Af + (size_t)grow * DM + k0 + c8 + 4);
          #pragma unroll
          for (int j = 0; j < 4; j++){ val[j] = (short)f2bf(f0[j]); val[4 + j] = (short)f2bf(f1[j]); }
        }
        *reinterpret_cast<s16x8*>(&As[rr * LDAS + c8]) = val;
      }
    }
    __syncthreads();

    // B fragments direct from global (f32 -> bf16). k = k0 + 16h + 4*lg + i.
    s16x8 bfrag[2];
    #pragma unroll
    for (int ni = 0; ni < 2; ni++){
      const int gn = n0 + wc * 32 + ni * 16 + l15;
      #pragma unroll
      for (int h = 0; h < 2; h++)
        #pragma unroll
        for (int i2 = 0; i2 < 4; i2++){
          const int kk = k0 + 16 * h + 4 * lg + i2;
          bfrag[ni][h * 4 + i2] = (short)f2bf(B[(size_t)kk * DM + gn]);
        }
    }

    #pragma unroll
    for (int mi = 0; mi < 4; mi++){
      const int rl = wr * 64 + mi * 16 + l15;
      s16x4 lo = *reinterpret_cast<const s16x4*>(&As[rl * LDAS + 4 * lg]);
      s16x4 hi = *reinterpret_cast<const s16x4*>(&As[rl * LDAS + 16 + 4 * lg]);
      s16x8 af;
      af[0]=lo[0]; af[1]=lo[1]; af[2]=lo[2]; af[3]=lo[3];
      af[4]=hi[0]; af[5]=hi[1]; af[6]=hi[2]; af[7]=hi[3];
      #pragma unroll
      for (int ni = 0; ni < 2; ni++)
        acc[mi][ni] = __builtin_amdgcn_mfma_f32_16x16x32_bf16(af, bfrag[ni], acc[mi][ni], 0, 0, 0);
    }
  }

  // epilogue: C row = 4*(lane>>4) + reg, col = lane&15  (m89-verified layout)
  #pragma unroll
  for (int mi = 0; mi < 4; mi++)
    #pragma unroll
    for (int ni = 0; ni < 2; ni++){
      const int gn = n0 + wc * 32 + ni * 16 + l15;
      #pragma unroll
      for (int r = 0; r < 4; r++){
        const int gm = m0 + wr * 64 + mi * 16 + lg * 4 + r;
        if (gm < BROWS){
          const float val = acc[mi][ni][r];
          if (MODE == 0){
            Cb[(size_t)gm * DM + gn] = f2bf(val * scale);
          } else {
            Cf[(size_t)gm * DM + gn] = val + bias[gn] + resid[(size_t)gm * DM + gn];
          }
        }
      }
    }
}

// ---------------------------------------------------------------- sparse PAM attention
// One block per (b, i) row; 4 waves x 4 heads. Each query attends <= 10 keys:
// intra window [i-2, i+2] clipped to level, 4 children (lvl>=1), parent (lvl<=2).
__global__ __launch_bounds__(256) void attn_kernel(const ushort_t* __restrict__ Q,
    const ushort_t* __restrict__ K, const ushort_t* __restrict__ V,
    ushort_t* __restrict__ ctx){
  const int row = blockIdx.x;           // b*1360 + i
  const int i = row % L_TOT;
  const int brow0 = row - i;            // b*1360
  const int wid = threadIdx.x >> 6, lane = threadIdx.x & 63;

  int st, sz, lvl;
  if      (i < 1024){ st = 0;    sz = 1024; lvl = 0; }
  else if (i < 1280){ st = 1024; sz = 256;  lvl = 1; }
  else if (i < 1344){ st = 1280; sz = 64;   lvl = 2; }
  else              { st = 1344; sz = 16;   lvl = 3; }

  int keys[10];
  int nk = 0;
  const int jl = (i - 2 < st) ? st : i - 2;
  const int jr = (i + 3 > st + sz) ? st + sz : i + 3;
  for (int j = jl; j < jr; j++) keys[nk++] = j;
  if (lvl >= 1){
    const int cs = st - sz * 4 + (i - st) * 4;   // child_start + (i-start)*4
    keys[nk] = cs; keys[nk+1] = cs+1; keys[nk+2] = cs+2; keys[nk+3] = cs+3; nk += 4;
  }
  if (lvl <= 2){ keys[nk++] = st + sz + ((i - st) >> 2); }   // parent

  #pragma unroll
  for (int hh = 0; hh < 4; hh++){
    const int h = wid * 4 + hh;
    const int col = h * 64 + lane;
    const float qv = b2f(Q[(size_t)row * DM + col]);   // Q already scaled by 1/8

    float s[10];
    #pragma unroll
    for (int k2 = 0; k2 < 10; k2++){
      float sc = -3.0e38f;
      if (k2 < nk){
        const float kv = b2f(K[(size_t)(brow0 + keys[k2]) * DM + col]);
        float p = qv * kv;
        p += __shfl_xor(p, 32); p += __shfl_xor(p, 16); p += __shfl_xor(p, 8);
        p += __shfl_xor(p, 4);  p += __shfl_xor(p, 2);  p += __shfl_xor(p, 1);
        sc = p;
      }
      s[k2] = sc;
    }
    float m = s[0];
    #pragma unroll
    for (int k2 = 1; k2 < 10; k2++) m = fmaxf(m, s[k2]);
    float p[10]; float sum = 0.f;
    #pragma unroll
    for (int k2 = 0; k2 < 10; k2++){
      const float e = (k2 < nk) ? __expf(s[k2] - m) : 0.f;
      p[k2] = e; sum += e;
    }
    const float inv = 1.0f / sum;
    float accv = 0.f;
    #pragma unroll
    for (int k2 = 0; k2 < 10; k2++){
      if (k2 < nk) accv += p[k2] * b2f(V[(size_t)(brow0 + keys[k2]) * DM + col]);
    }
    ctx[(size_t)row * DM + col] = f2bf(accv * inv);
  }
}

// ---------------------------------------------------------------- launch
extern "C" void kernel_launch(void* const* d_in, const int* in_sizes, int n_in,
                              void* d_out, int out_size, void* d_ws, size_t ws_size,
                              hipStream_t stream){
  (void)in_sizes; (void)n_in; (void)out_size; (void)ws_size;
  const float* x     = (const float*)d_in[0];
  const float* Wq    = (const float*)d_in[1];
  const float* Wk    = (const float*)d_in[2];
  const float* Wv    = (const float*)d_in[3];
  const float* Wfc   = (const float*)d_in[4];
  const float* bfc   = (const float*)d_in[5];
  const float* gamma = (const float*)d_in[6];
  const float* beta  = (const float*)d_in[7];
  // d_in[8] = mask: reconstructed analytically on-device, not read.
  float* out = (float*)d_out;

  char* ws = (char*)d_ws;
  const size_t SLAB = (size_t)BROWS * DM * sizeof(ushort_t);   // 11,141,120 B
  ushort_t* xln = (ushort_t*)(ws);              // LN(x) bf16; later reused as ctx
  ushort_t* Qb  = (ushort_t*)(ws + SLAB);
  ushort_t* Kb  = (ushort_t*)(ws + 2 * SLAB);
  ushort_t* Vb  = (ushort_t*)(ws + 3 * SLAB);
  ushort_t* ctx = xln;                          // xln dead after Q GEMM

  ln_kernel<<<BROWS, 256, 0, stream>>>(x, gamma, beta, xln);

  dim3 gg(DM / BN, (BROWS + BM - 1) / BM, 1);   // (16, 43)
  // Q = LN(x) @ Wq * (1/sqrt(64))
  gemm_kernel<true, 0><<<gg, 256, 0, stream>>>(xln, Wq, Qb, nullptr, nullptr, nullptr, 0.125f);
  // K = x @ Wk ; V = x @ Wv   (raw x, f32 A converted during staging)
  gemm_kernel<false, 0><<<gg, 256, 0, stream>>>(x, Wk, Kb, nullptr, nullptr, nullptr, 1.0f);
  gemm_kernel<false, 0><<<gg, 256, 0, stream>>>(x, Wv, Vb, nullptr, nullptr, nullptr, 1.0f);

  attn_kernel<<<BROWS, 256, 0, stream>>>(Qb, Kb, Vb, ctx);

  // out = ctx @ Wfc + bfc + x
  gemm_kernel<true, 1><<<gg, 256, 0, stream>>>(ctx, Wfc, nullptr, out, bfc, x, 1.0f);
}

// Round 2
// 180.345 us; speedup vs baseline: 1.5952x; 1.5952x over previous
//
#include <hip/hip_runtime.h>

typedef float f32x4 __attribute__((ext_vector_type(4)));
typedef short s16x8 __attribute__((ext_vector_type(8)));
typedef short s16x4 __attribute__((ext_vector_type(4)));
typedef unsigned short ushort_t;

#define L_TOT 1360
#define BROWS 5440   // 4 * 1360
#define DM    1024

__device__ __forceinline__ float b2f(ushort_t u){
  union { unsigned int u; float f; } v; v.u = ((unsigned int)u) << 16; return v.f;
}
__device__ __forceinline__ ushort_t f2bf(float f){
  union { float f; unsigned int u; } v; v.f = f;
  unsigned int u = v.u;
  unsigned int r = u + 0x7fffu + ((u >> 16) & 1u);
  return (ushort_t)(r >> 16);
}
// packed f32x2 -> bf16x2 (low = first arg)  [T12 recipe, gfx950]
__device__ __forceinline__ unsigned cvtpk(float lo, float hi){
  unsigned r; asm("v_cvt_pk_bf16_f32 %0, %1, %2" : "=v"(r) : "v"(lo), "v"(hi)); return r;
}

// ---------------------------------------------------------------- LayerNorm
__global__ __launch_bounds__(256) void ln_kernel(const float* __restrict__ x,
    const float* __restrict__ gamma, const float* __restrict__ beta,
    ushort_t* __restrict__ xln){
  const int row = blockIdx.x;
  const int t = threadIdx.x;
  const float* xr = x + (size_t)row * DM;
  f32x4 v = *reinterpret_cast<const f32x4*>(xr + t * 4);
  float s  = v.x + v.y + v.z + v.w;
  float s2 = v.x*v.x + v.y*v.y + v.z*v.z + v.w*v.w;
  #pragma unroll
  for (int off = 32; off; off >>= 1){ s += __shfl_xor(s, off); s2 += __shfl_xor(s2, off); }
  __shared__ float red[8];
  const int wid = t >> 6, lane = t & 63;
  if (lane == 0){ red[wid] = s; red[4 + wid] = s2; }
  __syncthreads();
  s  = red[0] + red[1] + red[2] + red[3];
  s2 = red[4] + red[5] + red[6] + red[7];
  const float mu  = s * (1.0f / DM);
  const float var = s2 * (1.0f / DM) - mu * mu;
  const float rs  = rsqrtf(var + 1e-6f);
  float y0 = (v.x - mu) * rs * gamma[t*4+0] + beta[t*4+0];
  float y1 = (v.y - mu) * rs * gamma[t*4+1] + beta[t*4+1];
  float y2 = (v.z - mu) * rs * gamma[t*4+2] + beta[t*4+2];
  float y3 = (v.w - mu) * rs * gamma[t*4+3] + beta[t*4+3];
  uint2 o; o.x = cvtpk(y0, y1); o.y = cvtpk(y2, y3);
  *reinterpret_cast<uint2*>(xln + (size_t)row * DM + t * 4) = o;
}

// ---------------------------------------------------------------- weight transpose
// W [1024][1024] f32  ->  D [1024][1024] bf16 transposed (D[n][k] = W[k][n])
__global__ __launch_bounds__(256) void trans_kernel(
    const float* __restrict__ W0, ushort_t* __restrict__ D0,
    const float* __restrict__ W1, ushort_t* __restrict__ D1,
    const float* __restrict__ W2, ushort_t* __restrict__ D2){
  const float* W = (blockIdx.z == 0) ? W0 : (blockIdx.z == 1) ? W1 : W2;
  ushort_t*    D = (blockIdx.z == 0) ? D0 : (blockIdx.z == 1) ? D1 : D2;
  __shared__ float sh[64][68];
  const int t = threadIdx.x;
  const int k0 = blockIdx.x * 64, n0 = blockIdx.y * 64;
  const int tr = t >> 4, tc = t & 15;
  #pragma unroll
  for (int it = 0; it < 4; it++){
    const int r = tr + it * 16;
    f32x4 v = *reinterpret_cast<const f32x4*>(W + (size_t)(k0 + r) * DM + n0 + tc * 4);
    *reinterpret_cast<f32x4*>(&sh[r][tc * 4]) = v;
  }
  __syncthreads();
  #pragma unroll
  for (int it = 0; it < 4; it++){
    const int rn = tr + it * 16;
    float a = sh[tc*4+0][rn], b = sh[tc*4+1][rn], c = sh[tc*4+2][rn], d = sh[tc*4+3][rn];
    uint2 w; w.x = cvtpk(a, b); w.y = cvtpk(c, d);
    *reinterpret_cast<uint2*>(D + (size_t)(n0 + rn) * DM + k0 + tc * 4) = w;
  }
}

// ---------------------------------------------------------------- GEMM
// C[5440 x Ntot] = A[5440 x 1024] * Bt^T  where Bt is [Ntot][1024] bf16 (pre-transposed).
// BM=128 BN=128 BK=32, 4 waves (2x2), wave tile 64x64 (4x4 16x16x32 frags).
// LDS rows hold k-chunks in interleaved order [q0 q4 q1 q5 q2 q6 q3 q7]
// (q = 4-element k-chunk) so an MFMA fragment = ONE ds_read_b128 at offset 8*lg.
#define LDAS 40

template<bool ABF16, int MODE>
__global__ __launch_bounds__(256) void gemm_kernel(const void* __restrict__ Ap,
    const ushort_t* __restrict__ Bt, ushort_t* __restrict__ Cb, float* __restrict__ Cf,
    const float* __restrict__ bias, const float* __restrict__ resid,
    float scale, int Ntot){
  __shared__ __align__(16) ushort_t As[128 * LDAS];
  __shared__ __align__(16) ushort_t Bs[128 * LDAS];
  const int tid = threadIdx.x;
  const int wid = tid >> 6, lane = tid & 63;
  const int l15 = lane & 15, lg = lane >> 4;
  const int wr = wid >> 1, wc = wid & 1;
  const int m0 = blockIdx.y * 128, n0 = blockIdx.x * 128;
  const ushort_t* Ab = (const ushort_t*)Ap;
  const float*    Af = (const float*)Ap;

  const int sr  = tid >> 1;          // staged row 0..127
  const int sj0 = (tid & 1) * 2;     // 16B chunk index {0,1} or {2,3}
  // interleave positions: chunk16 j -> short offsets of its two 4-chunks
  const int P0[4] = {0, 16, 4, 20};  // 4*pos(2j)
  const int P1[4] = {8, 24, 12, 28}; // 4*pos(2j+1)

  int garow = m0 + sr; if (garow > BROWS - 1) garow = BROWS - 1;
  const int gbrow = n0 + sr;

  f32x4 acc[4][4];
  #pragma unroll
  for (int a = 0; a < 4; a++)
    #pragma unroll
    for (int b = 0; b < 4; b++) acc[a][b] = (f32x4){0.f,0.f,0.f,0.f};

  for (int kt = 0; kt < DM / 32; ++kt){
    const int k0 = kt * 32;
    __syncthreads();
    #pragma unroll
    for (int u = 0; u < 2; u++){
      const int j = sj0 + u;
      // ---- A chunk
      s16x8 va;
      if (ABF16){
        va = *reinterpret_cast<const s16x8*>(Ab + (size_t)garow * DM + k0 + j * 8);
      } else {
        f32x4 f0 = *reinterpret_cast<const f32x4*>(Af + (size_t)garow * DM + k0 + j * 8);
        f32x4 f1 = *reinterpret_cast<const f32x4*>(Af + (size_t)garow * DM + k0 + j * 8 + 4);
        unsigned w0 = cvtpk(f0.x, f0.y), w1 = cvtpk(f0.z, f0.w);
        unsigned w2 = cvtpk(f1.x, f1.y), w3 = cvtpk(f1.z, f1.w);
        union { unsigned w[4]; s16x8 v; } u8; u8.w[0]=w0; u8.w[1]=w1; u8.w[2]=w2; u8.w[3]=w3;
        va = u8.v;
      }
      s16x4 alo, ahi;
      alo[0]=va[0]; alo[1]=va[1]; alo[2]=va[2]; alo[3]=va[3];
      ahi[0]=va[4]; ahi[1]=va[5]; ahi[2]=va[6]; ahi[3]=va[7];
      *reinterpret_cast<s16x4*>(&As[sr * LDAS + P0[j]]) = alo;
      *reinterpret_cast<s16x4*>(&As[sr * LDAS + P1[j]]) = ahi;
      // ---- B chunk
      s16x8 vb = *reinterpret_cast<const s16x8*>(Bt + (size_t)gbrow * DM + k0 + j * 8);
      s16x4 blo, bhi;
      blo[0]=vb[0]; blo[1]=vb[1]; blo[2]=vb[2]; blo[3]=vb[3];
      bhi[0]=vb[4]; bhi[1]=vb[5]; bhi[2]=vb[6]; bhi[3]=vb[7];
      *reinterpret_cast<s16x4*>(&Bs[sr * LDAS + P0[j]]) = blo;
      *reinterpret_cast<s16x4*>(&Bs[sr * LDAS + P1[j]]) = bhi;
    }
    __syncthreads();

    s16x8 af[4], bf[4];
    #pragma unroll
    for (int mi = 0; mi < 4; mi++)
      af[mi] = *reinterpret_cast<const s16x8*>(&As[(wr*64 + mi*16 + l15) * LDAS + lg * 8]);
    #pragma unroll
    for (int ni = 0; ni < 4; ni++)
      bf[ni] = *reinterpret_cast<const s16x8*>(&Bs[(wc*64 + ni*16 + l15) * LDAS + lg * 8]);
    #pragma unroll
    for (int mi = 0; mi < 4; mi++)
      #pragma unroll
      for (int ni = 0; ni < 4; ni++)
        acc[mi][ni] = __builtin_amdgcn_mfma_f32_16x16x32_bf16(af[mi], bf[ni], acc[mi][ni], 0, 0, 0);
  }

  // epilogue: frag row = 4*lg + r, col = l15
  #pragma unroll
  for (int mi = 0; mi < 4; mi++)
    #pragma unroll
    for (int ni = 0; ni < 4; ni++){
      const int gn = n0 + wc*64 + ni*16 + l15;
      #pragma unroll
      for (int r = 0; r < 4; r++){
        const int gm = m0 + wr*64 + mi*16 + lg*4 + r;
        if (gm < BROWS){
          const float val = acc[mi][ni][r];
          if (MODE == 0){
            Cb[(size_t)gm * Ntot + gn] = f2bf(val * scale);
          } else {
            Cf[(size_t)gm * Ntot + gn] = val + bias[gn] + resid[(size_t)gm * Ntot + gn];
          }
        }
      }
    }
}

// ---------------------------------------------------------------- sparse PAM attention
// Wave = 16 queries x 4 d-groups (lane = (l&15)=query, (l>>4)=16-d slice).
// Per lane: own softmax, 10 key slots (5 window, 4 children, 1 parent), 2 shuffles/key.
// KV layout: KVb[row][0..1023]=K, [1024..2047]=V. Writes ctx IN-PLACE over Q.
__global__ __launch_bounds__(256) void attn_kernel(const ushort_t* __restrict__ Q,
    const ushort_t* __restrict__ KV, ushort_t* __restrict__ ctx){
  const int wid = threadIdx.x >> 6, lane = threadIdx.x & 63;
  const int gw = blockIdx.x * 4 + wid;          // 0..5439
  const int b = gw / L_TOT;
  const int rem = gw - b * L_TOT;
  const int h = rem / 85;
  const int qt = rem - h * 85;
  const int l15 = lane & 15, g = lane >> 4;
  const int i = qt * 16 + l15;
  const int row = b * L_TOT + i;
  const int brow0 = b * L_TOT;

  int st, sz;
  if      (i < 1024){ st = 0;    sz = 1024; }
  else if (i < 1280){ st = 1024; sz = 256;  }
  else if (i < 1344){ st = 1280; sz = 64;   }
  else              { st = 1344; sz = 16;   }

  int key[10]; bool val[10];
  #pragma unroll
  for (int s = 0; s < 5; s++){
    int j = i - 2 + s;
    val[s] = (j >= st) && (j < st + sz);
    key[s] = val[s] ? j : i;
  }
  const bool haskid = (i >= 1024);
  const int cs = haskid ? (st - sz * 4 + (i - st) * 4) : i;
  #pragma unroll
  for (int c = 0; c < 4; c++){ key[5 + c] = haskid ? (cs + c) : i; val[5 + c] = haskid; }
  const bool haspar = (i < 1344);
  key[9] = haspar ? (st + sz + ((i - st) >> 2)) : i;
  val[9] = haspar;

  const int dcol = h * 64 + g * 16;
  const ushort_t* qp = Q + (size_t)row * DM + dcol;
  s16x8 q0 = *reinterpret_cast<const s16x8*>(qp);
  s16x8 q1 = *reinterpret_cast<const s16x8*>(qp + 8);
  float qf[16];
  #pragma unroll
  for (int j = 0; j < 8; j++){ qf[j] = b2f((ushort_t)q0[j]); qf[8 + j] = b2f((ushort_t)q1[j]); }

  size_t koff[10];
  float sc[10];
  #pragma unroll
  for (int s = 0; s < 10; s++){
    koff[s] = (size_t)(brow0 + key[s]) * 2048 + dcol;
    const ushort_t* kp = KV + koff[s];
    s16x8 k0 = *reinterpret_cast<const s16x8*>(kp);
    s16x8 k1 = *reinterpret_cast<const s16x8*>(kp + 8);
    float p = 0.f;
    #pragma unroll
    for (int j = 0; j < 8; j++){
      p += qf[j]     * b2f((ushort_t)k0[j]);
      p += qf[8 + j] * b2f((ushort_t)k1[j]);
    }
    p += __shfl_xor(p, 16);
    p += __shfl_xor(p, 32);
    sc[s] = val[s] ? p : -1e30f;
  }

  float m = sc[0];
  #pragma unroll
  for (int s = 1; s < 10; s++) m = fmaxf(m, sc[s]);
  float e[10]; float sum = 0.f;
  #pragma unroll
  for (int s = 0; s < 10; s++){ e[s] = __expf(sc[s] - m); sum += e[s]; }
  const float inv = 1.0f / sum;

  float accv[16];
  #pragma unroll
  for (int j = 0; j < 16; j++) accv[j] = 0.f;
  #pragma unroll
  for (int s = 0; s < 10; s++){
    const ushort_t* vp = KV + koff[s] + 1024;
    s16x8 v0 = *reinterpret_cast<const s16x8*>(vp);
    s16x8 v1 = *reinterpret_cast<const s16x8*>(vp + 8);
    const float w = e[s];
    #pragma unroll
    for (int j = 0; j < 8; j++){
      accv[j]     += w * b2f((ushort_t)v0[j]);
      accv[8 + j] += w * b2f((ushort_t)v1[j]);
    }
  }

  uint4 o0, o1;
  o0.x = cvtpk(accv[0]*inv,  accv[1]*inv);  o0.y = cvtpk(accv[2]*inv,  accv[3]*inv);
  o0.z = cvtpk(accv[4]*inv,  accv[5]*inv);  o0.w = cvtpk(accv[6]*inv,  accv[7]*inv);
  o1.x = cvtpk(accv[8]*inv,  accv[9]*inv);  o1.y = cvtpk(accv[10]*inv, accv[11]*inv);
  o1.z = cvtpk(accv[12]*inv, accv[13]*inv); o1.w = cvtpk(accv[14]*inv, accv[15]*inv);
  ushort_t* op = ctx + (size_t)row * DM + dcol;
  *reinterpret_cast<uint4*>(op) = o0;
  *reinterpret_cast<uint4*>(op + 8) = o1;
}

// ---------------------------------------------------------------- launch
extern "C" void kernel_launch(void* const* d_in, const int* in_sizes, int n_in,
                              void* d_out, int out_size, void* d_ws, size_t ws_size,
                              hipStream_t stream){
  (void)in_sizes; (void)n_in; (void)out_size; (void)ws_size;
  const float* x     = (const float*)d_in[0];
  const float* Wq    = (const float*)d_in[1];
  const float* Wk    = (const float*)d_in[2];
  const float* Wv    = (const float*)d_in[3];
  const float* Wfc   = (const float*)d_in[4];
  const float* bfc   = (const float*)d_in[5];
  const float* gamma = (const float*)d_in[6];
  const float* beta  = (const float*)d_in[7];
  float* out = (float*)d_out;

  char* ws = (char*)d_ws;
  const size_t SLAB = (size_t)BROWS * DM * sizeof(ushort_t);   // 11,141,120 B
  // C: xln (later Wkv_t [4MB] + Wfc_t [2MB]);  D: Qb -> ctx (in place);  E: Wq_t -> KVb
  ushort_t* Cr = (ushort_t*)(ws);
  ushort_t* Dr = (ushort_t*)(ws + SLAB);
  ushort_t* Er = (ushort_t*)(ws + 2 * SLAB);

  ushort_t* xln   = Cr;
  ushort_t* Qb    = Dr;
  ushort_t* Wq_t  = Er;                         // 2 MB, dead after Q GEMM
  ushort_t* Wkv_t = Cr;                         // 4 MB (rows 0-1023 = Wk^T, 1024-2047 = Wv^T)
  ushort_t* Wfc_t = Cr + 2 * 1024 * 1024;       // 2 MB
  ushort_t* KVb   = Er;                         // 22.3 MB
  ushort_t* ctx   = Dr;                         // in-place over Qb

  // 1) LN(x) -> xln (bf16)
  ln_kernel<<<BROWS, 256, 0, stream>>>(x, gamma, beta, xln);
  // 2) Wq^T -> E
  trans_kernel<<<dim3(16,16,1), 256, 0, stream>>>(Wq, Wq_t, Wq, Wq_t, Wq, Wq_t);
  // 3) Q = (xln @ Wq) * 0.125  -> D
  gemm_kernel<true, 0><<<dim3(8,43), 256, 0, stream>>>(xln, Wq_t, Qb, nullptr, nullptr, nullptr, 0.125f, 1024);
  // 4) Wk^T, Wv^T, Wfc^T -> C (xln dead)
  trans_kernel<<<dim3(16,16,3), 256, 0, stream>>>(Wk, Wkv_t, Wv, Wkv_t + 1024*1024, Wfc, Wfc_t);
  // 5) KV = x @ [Wk | Wv] -> E (stride 2048)
  gemm_kernel<false, 0><<<dim3(16,43), 256, 0, stream>>>(x, Wkv_t, KVb, nullptr, nullptr, nullptr, 1.0f, 2048);
  // 6) sparse attention: Q@D + KV@E -> ctx@D (in place)
  attn_kernel<<<L_TOT, 256, 0, stream>>>(Qb, KVb, ctx);
  // 7) out = ctx @ Wfc + bfc + x
  gemm_kernel<true, 1><<<dim3(8,43), 256, 0, stream>>>(ctx, Wfc_t, nullptr, out, bfc, x, 1.0f, 1024);
}

// Round 3
// 167.455 us; speedup vs baseline: 1.7180x; 1.0770x over previous
//
#include <hip/hip_runtime.h>

typedef float f32x4 __attribute__((ext_vector_type(4)));
typedef short s16x8 __attribute__((ext_vector_type(8)));
typedef short s16x4 __attribute__((ext_vector_type(4)));
typedef unsigned short ushort_t;

#define L_TOT 1360
#define BROWS 5440   // 4 * 1360
#define DM    1024
#define LDAS  40

__device__ __forceinline__ float b2f(ushort_t u){
  union { unsigned int u; float f; } v; v.u = ((unsigned int)u) << 16; return v.f;
}
__device__ __forceinline__ ushort_t f2bf(float f){
  union { float f; unsigned int u; } v; v.f = f;
  unsigned int u = v.u;
  unsigned int r = u + 0x7fffu + ((u >> 16) & 1u);
  return (ushort_t)(r >> 16);
}
// packed f32x2 -> bf16x2 (low = first arg)
__device__ __forceinline__ unsigned cvtpk(float lo, float hi){
  unsigned r; asm("v_cvt_pk_bf16_f32 %0, %1, %2" : "=v"(r) : "v"(lo), "v"(hi)); return r;
}
__device__ __forceinline__ s16x4 mk4(unsigned a, unsigned b){
  union { unsigned w[2]; s16x4 v; } u; u.w[0] = a; u.w[1] = b; return u.v;
}
// interleave positions (shorts) for 4-short half-chunks of a 32-k row:
// chunk j lo -> PL(j), hi -> PH(j); fragment read = b128 at 8*lg.
__device__ __forceinline__ int PL(int j){ return (j & 1) * 16 + (j >> 1) * 4; }
__device__ __forceinline__ int PH(int j){ return 8 + (j & 1) * 16 + (j >> 1) * 4; }

// ---------------------------------------------------------------- row stats (mu, rs)
__global__ __launch_bounds__(256) void stats_kernel(const float* __restrict__ x,
    float* __restrict__ mu, float* __restrict__ rs){
  const int row = blockIdx.x;
  const int t = threadIdx.x;
  f32x4 v = *reinterpret_cast<const f32x4*>(x + (size_t)row * DM + t * 4);
  float s  = v.x + v.y + v.z + v.w;
  float s2 = v.x*v.x + v.y*v.y + v.z*v.z + v.w*v.w;
  #pragma unroll
  for (int off = 32; off; off >>= 1){ s += __shfl_xor(s, off); s2 += __shfl_xor(s2, off); }
  __shared__ float red[8];
  const int wid = t >> 6, lane = t & 63;
  if (lane == 0){ red[wid] = s; red[4 + wid] = s2; }
  __syncthreads();
  if (t == 0){
    s  = red[0] + red[1] + red[2] + red[3];
    s2 = red[4] + red[5] + red[6] + red[7];
    const float m = s * (1.0f / DM);
    const float var = s2 * (1.0f / DM) - m * m;
    mu[row] = m;
    rs[row] = rsqrtf(var + 1e-6f);
  }
}

// ---------------------------------------------------------------- cvec: cg = gamma^T Wq, cb = beta^T Wq
__global__ __launch_bounds__(256) void cvec_kernel(const float* __restrict__ Wq,
    const float* __restrict__ gamma, const float* __restrict__ beta,
    float* __restrict__ cg, float* __restrict__ cb){
  const int t = threadIdx.x;
  const int c = t & 15;                  // col within block
  const int kq = t >> 4;                 // 0..15
  const int col = blockIdx.x * 16 + c;
  float sg = 0.f, sb = 0.f;
  for (int k = kq * 64; k < kq * 64 + 64; k++){
    const float w = Wq[(size_t)k * DM + col];
    sg += gamma[k] * w;
    sb += beta[k] * w;
  }
  __shared__ float shg[16][17], shb[16][17];
  shg[kq][c] = sg; shb[kq][c] = sb;
  __syncthreads();
  if (kq == 0){
    float tg = 0.f, tb = 0.f;
    #pragma unroll
    for (int q = 0; q < 16; q++){ tg += shg[q][c]; tb += shb[q][c]; }
    cg[col] = tg; cb[col] = tb;
  }
}

// ---------------------------------------------------------------- weight transpose
// z=0: diag(gamma)*Wq -> Wqkv_t rows 0-1023 ; z=1: Wk -> rows 1024-2047 ;
// z=2: Wv -> rows 2048-3071 ; z=3: Wfc -> Wfc_t.   All [1024][1024] f32 -> bf16 B^T.
__global__ __launch_bounds__(256) void trans_kernel(
    const float* __restrict__ Wq, const float* __restrict__ Wk,
    const float* __restrict__ Wv, const float* __restrict__ Wfc,
    const float* __restrict__ gamma,
    ushort_t* __restrict__ Wqkv_t, ushort_t* __restrict__ Wfc_t){
  const int z = blockIdx.z;
  const float* W = (z == 0) ? Wq : (z == 1) ? Wk : (z == 2) ? Wv : Wfc;
  ushort_t* D = (z == 3) ? Wfc_t : (Wqkv_t + (size_t)z * DM * DM);
  __shared__ float sh[64][68];
  const int t = threadIdx.x;
  const int k0 = blockIdx.x * 64, n0 = blockIdx.y * 64;
  const int tr = t >> 4, tc = t & 15;
  #pragma unroll
  for (int it = 0; it < 4; it++){
    const int r = tr + it * 16;
    f32x4 v = *reinterpret_cast<const f32x4*>(W + (size_t)(k0 + r) * DM + n0 + tc * 4);
    if (z == 0){ const float g = gamma[k0 + r]; v.x *= g; v.y *= g; v.z *= g; v.w *= g; }
    *reinterpret_cast<f32x4*>(&sh[r][tc * 4]) = v;
  }
  __syncthreads();
  #pragma unroll
  for (int it = 0; it < 4; it++){
    const int rn = tr + it * 16;
    float a = sh[tc*4+0][rn], b = sh[tc*4+1][rn], c = sh[tc*4+2][rn], d = sh[tc*4+3][rn];
    uint2 w; w.x = cvtpk(a, b); w.y = cvtpk(c, d);
    *reinterpret_cast<uint2*>(D + (size_t)(n0 + rn) * DM + k0 + tc * 4) = w;
  }
}

// ---------------------------------------------------------------- fused QKV GEMM
// A = x (f32, cvt in staging), B = Wqkv_t [3072][1024] bf16.
// flat grid 1032 = 43 m-tiles x 24 n-tiles. tx<8 -> Q (LN folded into epilogue),
// tx<16 -> K, else V. BM=BN=128, BK=32, 4 waves 2x2, reg-prefetch + LDS dbuf,
// ONE barrier per K-step.
__global__ __launch_bounds__(256) void qkv_gemm(const float* __restrict__ A,
    const ushort_t* __restrict__ Bt, ushort_t* __restrict__ Qb, ushort_t* __restrict__ KVb,
    const float* __restrict__ cg, const float* __restrict__ cb,
    const float* __restrict__ mu, const float* __restrict__ rs){
  __shared__ __align__(16) ushort_t As[2][128 * LDAS];
  __shared__ __align__(16) ushort_t Bs[2][128 * LDAS];
  const int tid = threadIdx.x;
  const int wid = tid >> 6, lane = tid & 63;
  const int l15 = lane & 15, lg = lane >> 4;
  const int wr = wid >> 1, wc = wid & 1;
  const int flat = blockIdx.x;
  const int ty = flat / 24, tx = flat % 24;
  const int m0 = ty * 128;
  const int brow0 = tx * 128;

  const int sr  = tid >> 1;
  const int j0  = (tid & 1) * 2, j1 = j0 + 1;
  int garow = m0 + sr; if (garow > BROWS - 1) garow = BROWS - 1;
  const float*    ap = A  + (size_t)garow * DM;
  const ushort_t* bp = Bt + (size_t)(brow0 + sr) * DM;

  f32x4 ra0, ra1, ra2, ra3; s16x8 rb0, rb1;
  #define QLOAD(K0) do { \
    ra0 = *reinterpret_cast<const f32x4*>(ap + (K0) + j0 * 8); \
    ra1 = *reinterpret_cast<const f32x4*>(ap + (K0) + j0 * 8 + 4); \
    ra2 = *reinterpret_cast<const f32x4*>(ap + (K0) + j1 * 8); \
    ra3 = *reinterpret_cast<const f32x4*>(ap + (K0) + j1 * 8 + 4); \
    rb0 = *reinterpret_cast<const s16x8*>(bp + (K0) + j0 * 8); \
    rb1 = *reinterpret_cast<const s16x8*>(bp + (K0) + j1 * 8); \
  } while(0)
  #define QWRITE(P) do { \
    *reinterpret_cast<s16x4*>(&As[P][sr * LDAS + PL(j0)]) = mk4(cvtpk(ra0.x, ra0.y), cvtpk(ra0.z, ra0.w)); \
    *reinterpret_cast<s16x4*>(&As[P][sr * LDAS + PH(j0)]) = mk4(cvtpk(ra1.x, ra1.y), cvtpk(ra1.z, ra1.w)); \
    *reinterpret_cast<s16x4*>(&As[P][sr * LDAS + PL(j1)]) = mk4(cvtpk(ra2.x, ra2.y), cvtpk(ra2.z, ra2.w)); \
    *reinterpret_cast<s16x4*>(&As[P][sr * LDAS + PH(j1)]) = mk4(cvtpk(ra3.x, ra3.y), cvtpk(ra3.z, ra3.w)); \
    s16x4 b0l, b0h, b1l, b1h; \
    b0l[0]=rb0[0]; b0l[1]=rb0[1]; b0l[2]=rb0[2]; b0l[3]=rb0[3]; \
    b0h[0]=rb0[4]; b0h[1]=rb0[5]; b0h[2]=rb0[6]; b0h[3]=rb0[7]; \
    b1l[0]=rb1[0]; b1l[1]=rb1[1]; b1l[2]=rb1[2]; b1l[3]=rb1[3]; \
    b1h[0]=rb1[4]; b1h[1]=rb1[5]; b1h[2]=rb1[6]; b1h[3]=rb1[7]; \
    *reinterpret_cast<s16x4*>(&Bs[P][sr * LDAS + PL(j0)]) = b0l; \
    *reinterpret_cast<s16x4*>(&Bs[P][sr * LDAS + PH(j0)]) = b0h; \
    *reinterpret_cast<s16x4*>(&Bs[P][sr * LDAS + PL(j1)]) = b1l; \
    *reinterpret_cast<s16x4*>(&Bs[P][sr * LDAS + PH(j1)]) = b1h; \
  } while(0)

  f32x4 acc[4][4];
  #pragma unroll
  for (int a = 0; a < 4; a++)
    #pragma unroll
    for (int b = 0; b < 4; b++) acc[a][b] = (f32x4){0.f,0.f,0.f,0.f};

  QLOAD(0);
  QWRITE(0);
  __syncthreads();

  for (int kt = 0; kt < 32; ++kt){
    const int p = kt & 1;
    if (kt < 31) QLOAD((kt + 1) * 32);

    s16x8 af[4], bf[4];
    #pragma unroll
    for (int mi = 0; mi < 4; mi++)
      af[mi] = *reinterpret_cast<const s16x8*>(&As[p][(wr*64 + mi*16 + l15) * LDAS + lg * 8]);
    #pragma unroll
    for (int ni = 0; ni < 4; ni++)
      bf[ni] = *reinterpret_cast<const s16x8*>(&Bs[p][(wc*64 + ni*16 + l15) * LDAS + lg * 8]);
    #pragma unroll
    for (int mi = 0; mi < 4; mi++)
      #pragma unroll
      for (int ni = 0; ni < 4; ni++)
        acc[mi][ni] = __builtin_amdgcn_mfma_f32_16x16x32_bf16(af[mi], bf[ni], acc[mi][ni], 0, 0, 0);

    if (kt < 31){
      QWRITE(p ^ 1);
      __syncthreads();
    }
  }
  #undef QLOAD
  #undef QWRITE

  // epilogue
  const bool isQ = (tx < 8);
  ushort_t* outp; int ostride, col0;
  if (tx < 8)      { outp = Qb;  ostride = 1024; col0 = tx * 128; }
  else if (tx < 16){ outp = KVb; ostride = 2048; col0 = (tx - 8) * 128; }
  else             { outp = KVb; ostride = 2048; col0 = 1024 + (tx - 16) * 128; }

  #pragma unroll
  for (int mi = 0; mi < 4; mi++){
    #pragma unroll
    for (int r = 0; r < 4; r++){
      const int gm = m0 + wr*64 + mi*16 + lg*4 + r;
      if (gm < BROWS){
        const float rsv = isQ ? rs[gm] : 0.f;
        const float muv = isQ ? mu[gm] : 0.f;
        #pragma unroll
        for (int ni = 0; ni < 4; ni++){
          const int nl = wc*64 + ni*16 + l15;
          float v = acc[mi][ni][r];
          if (isQ) v = 0.125f * (rsv * (v - muv * cg[brow0 + nl]) + cb[brow0 + nl]);
          outp[(size_t)gm * ostride + col0 + nl] = f2bf(v);
        }
      }
    }
  }
}

// ---------------------------------------------------------------- FC GEMM
// out = ctx @ Wfc + bias + resid.  BM=64, BN=128, grid 680 = 85 x 8.
__global__ __launch_bounds__(256) void fc_gemm(const ushort_t* __restrict__ A,
    const ushort_t* __restrict__ Bt, const float* __restrict__ bias,
    const float* __restrict__ resid, float* __restrict__ out){
  __shared__ __align__(16) ushort_t As[2][64 * LDAS];
  __shared__ __align__(16) ushort_t Bs[2][128 * LDAS];
  const int tid = threadIdx.x;
  const int wid = tid >> 6, lane = tid & 63;
  const int l15 = lane & 15, lg = lane >> 4;
  const int wr = wid >> 1, wc = wid & 1;
  const int ty = blockIdx.x >> 3, tx = blockIdx.x & 7;
  const int m0 = ty * 64, n0 = tx * 128;

  const int sra = tid >> 2, ja = tid & 3;           // A: 1 chunk
  const int srb = tid >> 1, jb0 = (tid & 1) * 2, jb1 = jb0 + 1;  // B: 2 chunks
  const ushort_t* apc = A  + (size_t)(m0 + sra) * DM;
  const ushort_t* bp  = Bt + (size_t)(n0 + srb) * DM;

  s16x8 raa, rb0, rb1;
  #define FLOAD(K0) do { \
    raa = *reinterpret_cast<const s16x8*>(apc + (K0) + ja * 8); \
    rb0 = *reinterpret_cast<const s16x8*>(bp + (K0) + jb0 * 8); \
    rb1 = *reinterpret_cast<const s16x8*>(bp + (K0) + jb1 * 8); \
  } while(0)
  #define FWRITE(P) do { \
    s16x4 al, ah, b0l, b0h, b1l, b1h; \
    al[0]=raa[0]; al[1]=raa[1]; al[2]=raa[2]; al[3]=raa[3]; \
    ah[0]=raa[4]; ah[1]=raa[5]; ah[2]=raa[6]; ah[3]=raa[7]; \
    b0l[0]=rb0[0]; b0l[1]=rb0[1]; b0l[2]=rb0[2]; b0l[3]=rb0[3]; \
    b0h[0]=rb0[4]; b0h[1]=rb0[5]; b0h[2]=rb0[6]; b0h[3]=rb0[7]; \
    b1l[0]=rb1[0]; b1l[1]=rb1[1]; b1l[2]=rb1[2]; b1l[3]=rb1[3]; \
    b1h[0]=rb1[4]; b1h[1]=rb1[5]; b1h[2]=rb1[6]; b1h[3]=rb1[7]; \
    *reinterpret_cast<s16x4*>(&As[P][sra * LDAS + PL(ja)]) = al; \
    *reinterpret_cast<s16x4*>(&As[P][sra * LDAS + PH(ja)]) = ah; \
    *reinterpret_cast<s16x4*>(&Bs[P][srb * LDAS + PL(jb0)]) = b0l; \
    *reinterpret_cast<s16x4*>(&Bs[P][srb * LDAS + PH(jb0)]) = b0h; \
    *reinterpret_cast<s16x4*>(&Bs[P][srb * LDAS + PL(jb1)]) = b1l; \
    *reinterpret_cast<s16x4*>(&Bs[P][srb * LDAS + PH(jb1)]) = b1h; \
  } while(0)

  f32x4 acc[2][4];
  #pragma unroll
  for (int a = 0; a < 2; a++)
    #pragma unroll
    for (int b = 0; b < 4; b++) acc[a][b] = (f32x4){0.f,0.f,0.f,0.f};

  FLOAD(0);
  FWRITE(0);
  __syncthreads();

  for (int kt = 0; kt < 32; ++kt){
    const int p = kt & 1;
    if (kt < 31) FLOAD((kt + 1) * 32);

    s16x8 af[2], bf[4];
    #pragma unroll
    for (int mi = 0; mi < 2; mi++)
      af[mi] = *reinterpret_cast<const s16x8*>(&As[p][(wr*32 + mi*16 + l15) * LDAS + lg * 8]);
    #pragma unroll
    for (int ni = 0; ni < 4; ni++)
      bf[ni] = *reinterpret_cast<const s16x8*>(&Bs[p][(wc*64 + ni*16 + l15) * LDAS + lg * 8]);
    #pragma unroll
    for (int mi = 0; mi < 2; mi++)
      #pragma unroll
      for (int ni = 0; ni < 4; ni++)
        acc[mi][ni] = __builtin_amdgcn_mfma_f32_16x16x32_bf16(af[mi], bf[ni], acc[mi][ni], 0, 0, 0);

    if (kt < 31){
      FWRITE(p ^ 1);
      __syncthreads();
    }
  }
  #undef FLOAD
  #undef FWRITE

  #pragma unroll
  for (int mi = 0; mi < 2; mi++)
    #pragma unroll
    for (int ni = 0; ni < 4; ni++){
      const int gn = n0 + wc*64 + ni*16 + l15;
      #pragma unroll
      for (int r = 0; r < 4; r++){
        const int gm = m0 + wr*32 + mi*16 + lg*4 + r;
        out[(size_t)gm * DM + gn] = acc[mi][ni][r] + bias[gn] + resid[(size_t)gm * DM + gn];
      }
    }
}

// ---------------------------------------------------------------- sparse PAM attention
__global__ __launch_bounds__(256) void attn_kernel(const ushort_t* __restrict__ Q,
    const ushort_t* __restrict__ KV, ushort_t* __restrict__ ctx){
  const int wid = threadIdx.x >> 6, lane = threadIdx.x & 63;
  const int gw = blockIdx.x * 4 + wid;
  const int b = gw / L_TOT;
  const int rem = gw - b * L_TOT;
  const int h = rem / 85;
  const int qt = rem - h * 85;
  const int l15 = lane & 15, g = lane >> 4;
  const int i = qt * 16 + l15;
  const int row = b * L_TOT + i;
  const int brow0 = b * L_TOT;

  int st, sz;
  if      (i < 1024){ st = 0;    sz = 1024; }
  else if (i < 1280){ st = 1024; sz = 256;  }
  else if (i < 1344){ st = 1280; sz = 64;   }
  else              { st = 1344; sz = 16;   }

  int key[10]; bool val[10];
  #pragma unroll
  for (int s = 0; s < 5; s++){
    int j = i - 2 + s;
    val[s] = (j >= st) && (j < st + sz);
    key[s] = val[s] ? j : i;
  }
  const bool haskid = (i >= 1024);
  const int cs = haskid ? (st - sz * 4 + (i - st) * 4) : i;
  #pragma unroll
  for (int c = 0; c < 4; c++){ key[5 + c] = haskid ? (cs + c) : i; val[5 + c] = haskid; }
  const bool haspar = (i < 1344);
  key[9] = haspar ? (st + sz + ((i - st) >> 2)) : i;
  val[9] = haspar;

  const int dcol = h * 64 + g * 16;
  const ushort_t* qp = Q + (size_t)row * DM + dcol;
  s16x8 q0 = *reinterpret_cast<const s16x8*>(qp);
  s16x8 q1 = *reinterpret_cast<const s16x8*>(qp + 8);
  float qf[16];
  #pragma unroll
  for (int j = 0; j < 8; j++){ qf[j] = b2f((ushort_t)q0[j]); qf[8 + j] = b2f((ushort_t)q1[j]); }

  size_t koff[10];
  float sc[10];
  #pragma unroll
  for (int s = 0; s < 10; s++){
    koff[s] = (size_t)(brow0 + key[s]) * 2048 + dcol;
    const ushort_t* kp = KV + koff[s];
    s16x8 k0 = *reinterpret_cast<const s16x8*>(kp);
    s16x8 k1 = *reinterpret_cast<const s16x8*>(kp + 8);
    float p = 0.f;
    #pragma unroll
    for (int j = 0; j < 8; j++){
      p += qf[j]     * b2f((ushort_t)k0[j]);
      p += qf[8 + j] * b2f((ushort_t)k1[j]);
    }
    p += __shfl_xor(p, 16);
    p += __shfl_xor(p, 32);
    sc[s] = val[s] ? p : -1e30f;
  }

  float m = sc[0];
  #pragma unroll
  for (int s = 1; s < 10; s++) m = fmaxf(m, sc[s]);
  float e[10]; float sum = 0.f;
  #pragma unroll
  for (int s = 0; s < 10; s++){ e[s] = __expf(sc[s] - m); sum += e[s]; }
  const float inv = 1.0f / sum;

  float accv[16];
  #pragma unroll
  for (int j = 0; j < 16; j++) accv[j] = 0.f;
  #pragma unroll
  for (int s = 0; s < 10; s++){
    const ushort_t* vp = KV + koff[s] + 1024;
    s16x8 v0 = *reinterpret_cast<const s16x8*>(vp);
    s16x8 v1 = *reinterpret_cast<const s16x8*>(vp + 8);
    const float w = e[s];
    #pragma unroll
    for (int j = 0; j < 8; j++){
      accv[j]     += w * b2f((ushort_t)v0[j]);
      accv[8 + j] += w * b2f((ushort_t)v1[j]);
    }
  }

  uint4 o0, o1;
  o0.x = cvtpk(accv[0]*inv,  accv[1]*inv);  o0.y = cvtpk(accv[2]*inv,  accv[3]*inv);
  o0.z = cvtpk(accv[4]*inv,  accv[5]*inv);  o0.w = cvtpk(accv[6]*inv,  accv[7]*inv);
  o1.x = cvtpk(accv[8]*inv,  accv[9]*inv);  o1.y = cvtpk(accv[10]*inv, accv[11]*inv);
  o1.z = cvtpk(accv[12]*inv, accv[13]*inv); o1.w = cvtpk(accv[14]*inv, accv[15]*inv);
  ushort_t* op = ctx + (size_t)row * DM + dcol;
  *reinterpret_cast<uint4*>(op) = o0;
  *reinterpret_cast<uint4*>(op + 8) = o1;
}

// ---------------------------------------------------------------- launch
extern "C" void kernel_launch(void* const* d_in, const int* in_sizes, int n_in,
                              void* d_out, int out_size, void* d_ws, size_t ws_size,
                              hipStream_t stream){
  (void)in_sizes; (void)n_in; (void)out_size; (void)ws_size;
  const float* x     = (const float*)d_in[0];
  const float* Wq    = (const float*)d_in[1];
  const float* Wk    = (const float*)d_in[2];
  const float* Wv    = (const float*)d_in[3];
  const float* Wfc   = (const float*)d_in[4];
  const float* bfc   = (const float*)d_in[5];
  const float* gamma = (const float*)d_in[6];
  const float* beta  = (const float*)d_in[7];
  float* out = (float*)d_out;

  char* ws = (char*)d_ws;
  const size_t SLAB = (size_t)BROWS * DM * sizeof(ushort_t);   // 11,141,120 B
  // Region C [0, SLAB): weights + vectors
  ushort_t* Wqkv_t = (ushort_t*)(ws);                           // 6 MB
  ushort_t* Wfc_t  = (ushort_t*)(ws + 6291456);                 // 2 MB
  float*    cg     = (float*)(ws + 8388608);                    // 4 KB
  float*    cb     = (float*)(ws + 8392704);                    // 4 KB
  float*    muv    = (float*)(ws + 8396800);                    // 21.25 KB
  float*    rsv    = (float*)(ws + 8418560);                    // 21.25 KB
  // Region D [SLAB, 2*SLAB): Q -> ctx (in place)
  ushort_t* Qb  = (ushort_t*)(ws + SLAB);
  ushort_t* ctx = Qb;
  // Region E [2*SLAB, 4*SLAB): KV interleaved [row][K|V] stride 2048
  ushort_t* KVb = (ushort_t*)(ws + 2 * SLAB);

  stats_kernel<<<BROWS, 256, 0, stream>>>(x, muv, rsv);
  cvec_kernel<<<64, 256, 0, stream>>>(Wq, gamma, beta, cg, cb);
  trans_kernel<<<dim3(16, 16, 4), 256, 0, stream>>>(Wq, Wk, Wv, Wfc, gamma, Wqkv_t, Wfc_t);
  qkv_gemm<<<1032, 256, 0, stream>>>(x, Wqkv_t, Qb, KVb, cg, cb, muv, rsv);
  attn_kernel<<<L_TOT, 256, 0, stream>>>(Qb, KVb, ctx);
  fc_gemm<<<680, 256, 0, stream>>>(ctx, Wfc_t, bfc, x, out);
}